// Round 1
// 510.680 us; speedup vs baseline: 1.0312x; 1.0312x over previous
//
#include <hip/hip_runtime.h>
#include <hip/hip_bf16.h>
#include <math.h>

#define NB 16          // batch
#define NC 256         // channels
#define NPTS 1000      // P*K points per batch
#define NN2 2000       // P*K*2
#define D1 1024        // FC1 hidden
#define KFLAT 16384    // C*64

typedef unsigned short ushort8 __attribute__((ext_vector_type(8)));

static __device__ __forceinline__ float bf2f(unsigned short v) {
    union { unsigned int u; float f; } x;
    x.u = ((unsigned int)v) << 16;
    return x.f;
}

// ---------------- kernel 0: pool p4 + transpose small weights (fused)
// blocks [0,1024): 4x4 avg pool p4 (16,256,32,32) -> flat_bf (16,16384) bf16
// blocks [1024,1204): R1 [128][258] -> R1t [258][128]; V1 [128][100] -> V1t [100][128]
__global__ __launch_bounds__(256) void k_poolprep(const float* __restrict__ p4,
                                                  const float* __restrict__ R1,
                                                  const float* __restrict__ V1,
                                                  __hip_bfloat16* __restrict__ flat_bf,
                                                  float* __restrict__ R1t,
                                                  float* __restrict__ V1t_g) {
    int idx = blockIdx.x * 256 + threadIdx.x;
    if (idx < 262144) {                          // 16*16384 pool outputs
        int bc = idx >> 6;                       // b*256 + c
        int ij = idx & 63;
        int i = ij >> 3, j = ij & 7;
        const float* src = p4 + ((size_t)bc * 32 + i * 4) * 32 + j * 4;
        float s = 0.f;
#pragma unroll
        for (int di = 0; di < 4; ++di) {
            float4 v = *reinterpret_cast<const float4*>(src + di * 32);
            s += v.x + v.y + v.z + v.w;
        }
        flat_bf[idx] = __float2bfloat16(s * (1.0f / 16.0f));
    } else {
        int t = idx - 262144;
        if (t < 33024) {                         // 128*258
            int j = t / 258, k = t % 258;
            R1t[k * 128 + j] = R1[t];
        } else if (t < 33024 + 12800) {          // 128*100
            int t2 = t - 33024;
            int j = t2 / 100, k = t2 % 100;
            V1t_g[k * 128 + j] = V1[t2];
        }
    }
}

// ---------------- kernel 1: h = relu(flat @ W1^T + b1)  (16 x 1024)
// 512 threads = 8 waves: wave (half*4 + colw): column blk*4+colw, K-half `half`.
// flat staged in LDS as bf16; W1 2x float4/lane/iter with cross-barrier prefetch.
__global__ __launch_bounds__(512) void k_fc1(const __hip_bfloat16* __restrict__ flat_bf,
                                             const float* __restrict__ W1,
                                             const float* __restrict__ b1,
                                             float* __restrict__ h) {
    __shared__ unsigned short tile[2 * 16 * 512];   // 32 KB, [half][m][512] bf16
    __shared__ float red[8 * 16];
    const int tid = threadIdx.x;
    const int wave = tid >> 6, lane = tid & 63;
    const int colw = wave & 3, half = wave >> 2;
    const int n = blockIdx.x * 4 + colw;            // [0,1024)
    float acc[16];
#pragma unroll
    for (int m = 0; m < 16; ++m) acc[m] = 0.f;
    const float4* W1r4 = reinterpret_cast<const float4*>(W1 + (size_t)n * KFLAT + half * 8192);
    const ushort8* flat8 = reinterpret_cast<const ushort8*>(flat_bf);
    ushort8* tile8 = reinterpret_cast<ushort8*>(tile);

    float4 wa = W1r4[lane * 2], wb = W1r4[lane * 2 + 1];
    for (int it = 0; it < 16; ++it) {
        __syncthreads();                             // prev compute done with LDS
#pragma unroll
        for (int r = 0; r < 4; ++r) {
            int idx = tid + r * 512;                 // [0,2048) ushort8 chunks
            int hh = idx >> 10, m = (idx >> 6) & 15, off = idx & 63;
            tile8[idx] = flat8[m * 2048 + hh * 1024 + it * 64 + off];
        }
        __syncthreads();
        float4 na = wa, nb = wb;
        if (it < 15) {
            na = W1r4[(it + 1) * 128 + lane * 2];
            nb = W1r4[(it + 1) * 128 + lane * 2 + 1];
        }
#pragma unroll
        for (int m = 0; m < 16; ++m) {
            ushort8 u = tile8[half * 1024 + m * 64 + lane];
            float s = wa.x * bf2f(u.s0) + wa.y * bf2f(u.s1)
                    + wa.z * bf2f(u.s2) + wa.w * bf2f(u.s3)
                    + wb.x * bf2f(u.s4) + wb.y * bf2f(u.s5)
                    + wb.z * bf2f(u.s6) + wb.w * bf2f(u.s7);
            acc[m] += s;
        }
        wa = na; wb = nb;
    }
#pragma unroll
    for (int m = 0; m < 16; ++m) {
        float v = acc[m];
#pragma unroll
        for (int off = 32; off > 0; off >>= 1) v += __shfl_xor(v, off, 64);
        acc[m] = v;
    }
    __syncthreads();
    if (lane == 0) {
#pragma unroll
        for (int m = 0; m < 16; ++m) red[wave * 16 + m] = acc[m];
    }
    __syncthreads();
    if (tid < 64) {
        int c = tid >> 4, m = tid & 15;
        float v = red[c * 16 + m] + red[(c + 4) * 16 + m] + b1[blockIdx.x * 4 + c];
        h[m * D1 + blockIdx.x * 4 + c] = fmaxf(v, 0.f);
    }
}

// ---------------- kernel 2: init = sigmoid(h @ W2^T + b2)  (16 x 2000)
__global__ __launch_bounds__(256) void k_fc2(const float* __restrict__ h,
                                             const float* __restrict__ W2,
                                             const float* __restrict__ b2,
                                             float* __restrict__ init_ws,
                                             float* __restrict__ out_init) {
    const int tid = threadIdx.x;
    const int wave = tid >> 6, lane = tid & 63;
    const int n = blockIdx.x * 4 + wave;        // [0,2000)
    float acc[16];
#pragma unroll
    for (int m = 0; m < 16; ++m) acc[m] = 0.f;
    const float4* W2r = reinterpret_cast<const float4*>(W2 + (size_t)n * D1);
    const float4* h4  = reinterpret_cast<const float4*>(h);
#pragma unroll
    for (int it = 0; it < 4; ++it) {
        int k4 = it * 64 + lane;                // float4 idx in row (256/row)
        float4 w = W2r[k4];
#pragma unroll
        for (int m = 0; m < 16; ++m) {
            float4 f = h4[m * 256 + k4];
            acc[m] += w.x * f.x + w.y * f.y + w.z * f.z + w.w * f.w;
        }
    }
    float bias = b2[n];
#pragma unroll
    for (int m = 0; m < 16; ++m) {
        float v = acc[m];
#pragma unroll
        for (int off = 32; off > 0; off >>= 1) v += __shfl_xor(v, off, 64);
        if (lane == 0) {
            float s = 1.f / (1.f + expf(-(v + bias)));
            init_ws[m * NN2 + n] = s;
            out_init[m * NN2 + n] = s;
        }
    }
}

// ---------------- kernel 3: bilinear sample, one block per (b,c) image
// Whole 64KB image staged into LDS with coalesced float4 loads.
// sampled layout: bf16 [b][c][n]
__global__ __launch_bounds__(1024) void k_sample(const float* __restrict__ p2,
                                                 const float* __restrict__ init_ws,
                                                 __hip_bfloat16* __restrict__ sampled) {
    __shared__ float img[128 * 128];            // 64 KB -> 2 blocks/CU
    const int bc = blockIdx.x;                  // b*256 + c
    const int b = bc >> 8;
    const float4* src4 = reinterpret_cast<const float4*>(p2 + (size_t)bc * 16384);
    float4* dst4 = reinterpret_cast<float4*>(img);
#pragma unroll
    for (int i = 0; i < 4; ++i)
        dst4[threadIdx.x + i * 1024] = src4[threadIdx.x + i * 1024];
    __syncthreads();
    const float* ip = init_ws + b * NN2;
    const int n = threadIdx.x;
    if (n < NPTS) {
        float2 sxy = *reinterpret_cast<const float2*>(ip + 2 * n);
        float x = sxy.x * 128.f - 0.5f;
        float y = sxy.y * 128.f - 0.5f;
        float x0f = floorf(x), y0f = floorf(y);
        float wx = x - x0f, wy = y - y0f;
        int x0 = (int)x0f, y0 = (int)y0f;
        int x1 = x0 + 1, y1 = y0 + 1;
        bool vx0 = (x0 >= 0) && (x0 <= 127);
        bool vx1 = (x1 >= 0) && (x1 <= 127);
        bool vy0 = (y0 >= 0) && (y0 <= 127);
        bool vy1 = (y1 >= 0) && (y1 <= 127);
        int cx0 = min(max(x0, 0), 127), cx1 = min(max(x1, 0), 127);
        int cy0 = min(max(y0, 0), 127), cy1 = min(max(y1, 0), 127);
        float v00 = (vx0 && vy0) ? img[cy0 * 128 + cx0] : 0.f;
        float v10 = (vx1 && vy0) ? img[cy0 * 128 + cx1] : 0.f;
        float v01 = (vx0 && vy1) ? img[cy1 * 128 + cx0] : 0.f;
        float v11 = (vx1 && vy1) ? img[cy1 * 128 + cx1] : 0.f;
        float r = v00 * (1.f - wx) * (1.f - wy) + v10 * wx * (1.f - wy)
                + v01 * (1.f - wx) * wy + v11 * wx * wy;
        sampled[(size_t)bc * NPTS + n] = __float2bfloat16(r);
    }
}

// ---------------- kernel 4: FUSED refine head
// Phase 1: h1[j][n] = relu(feat @ R1^T + rb1) for a 64-point tile (all 128 j),
//          h1 kept in LDS (no h1t round-trip).
// Phase 2: h2 = relu(h1@R2^T+rb2); disp = tanh(h2@R3^T+rb3);
//          refined = clip(init + 0.1*disp).
// 256 threads = 4 waves. Per-lane 8j x 4n GEMM tile: 3 ds_read_b128 per 32 FMA
// (was 3 reads per 16 FMA in the old k_r1) -> LDS-throughput bound at ~15us.
// LDS union (48 KB): [As 32K | Bs 16K] then [hbuf 32K | part 2K].
__global__ __launch_bounds__(256) void k_refine(const __hip_bfloat16* __restrict__ sampled,
                                                const float* __restrict__ init_ws,
                                                const float* __restrict__ R1t,
                                                const float* __restrict__ rb1,
                                                const float* __restrict__ R2,
                                                const float* __restrict__ rb2,
                                                const float* __restrict__ R3,
                                                const float* __restrict__ rb3,
                                                float* __restrict__ refined) {
    __shared__ float smem[12288];   // 48 KB
    // phase 1: As = smem[0..8192) [kk][128j], Bs = smem[8192..12288) [kk][64n]
    // phase 2: hbuf = smem[0..8192) [128j][64n], part = smem[8192..8704)
    const int tid = threadIdx.x;
    const int b = blockIdx.x >> 4;
    const int n0 = (blockIdx.x & 15) * 64;
    const int jt = tid >> 4;        // [0,16): 8 j's (jt*4.. and 64+jt*4..)
    const int nt = tid & 15;        // [0,16): 4 n's (n0+nt*4..)
    float acc[8][4];
#pragma unroll
    for (int a = 0; a < 8; ++a)
#pragma unroll
        for (int c = 0; c < 4; ++c) acc[a][c] = 0.f;

    const float4* R1t4 = reinterpret_cast<const float4*>(R1t);
    float4* As4 = reinterpret_cast<float4*>(smem);

    for (int k0 = 0; k0 < 256; k0 += 64) {
        __syncthreads();            // previous compute done with As/Bs
        // stage As: 64 rows x 128 j = 2048 float4, coalesced from R1t
#pragma unroll
        for (int i = 0; i < 8; ++i) {
            int idx4 = tid + i * 256;                // kk*32 + r4
            As4[idx4] = R1t4[k0 * 32 + idx4];
        }
        // stage Bs: 64 rows x 64 n bf16 -> f32, vectorized ushort8 loads.
        // NPTS=1000 and n0,off*8 multiples of 8 => per-chunk all-or-nothing bound.
#pragma unroll
        for (int c2 = 0; c2 < 2; ++c2) {
            int chunk = tid + c2 * 256;              // [0,512)
            int row = chunk >> 3, off = chunk & 7;
            int nb = n0 + off * 8;
            float4 f0 = make_float4(0.f, 0.f, 0.f, 0.f);
            float4 f1 = make_float4(0.f, 0.f, 0.f, 0.f);
            if (nb + 8 <= NPTS) {
                ushort8 u = *reinterpret_cast<const ushort8*>(
                    reinterpret_cast<const unsigned short*>(sampled)
                    + ((size_t)(b * 256 + k0 + row)) * NPTS + nb);
                f0 = make_float4(bf2f(u.s0), bf2f(u.s1), bf2f(u.s2), bf2f(u.s3));
                f1 = make_float4(bf2f(u.s4), bf2f(u.s5), bf2f(u.s6), bf2f(u.s7));
            }
            float* bp = &smem[8192 + row * 64 + off * 8];
            *reinterpret_cast<float4*>(bp) = f0;
            *reinterpret_cast<float4*>(bp + 4) = f1;
        }
        __syncthreads();
#pragma unroll 4
        for (int kk = 0; kk < 64; ++kk) {
            const float* Ar = &smem[kk * 128];
            const float* Br = &smem[8192 + kk * 64];
            float4 a0 = *reinterpret_cast<const float4*>(Ar + jt * 4);
            float4 a1 = *reinterpret_cast<const float4*>(Ar + 64 + jt * 4);
            float4 bb = *reinterpret_cast<const float4*>(Br + nt * 4);
            float av[8] = {a0.x, a0.y, a0.z, a0.w, a1.x, a1.y, a1.z, a1.w};
            float bv[4] = {bb.x, bb.y, bb.z, bb.w};
#pragma unroll
            for (int a = 0; a < 8; ++a)
#pragma unroll
                for (int c = 0; c < 4; ++c)
                    acc[a][c] = fmaf(av[a], bv[c], acc[a][c]);
        }
    }
    // phase-1 epilogue: coord columns (K=256,257) + bias + relu -> hbuf in LDS.
    // coord reads for n>=NPTS land in later ws regions (in-bounds, garbage ok,
    // final store is guarded).
    const int nbase = n0 + nt * 4;
    float4 cA = *reinterpret_cast<const float4*>(init_ws + b * NN2 + 2 * nbase);
    float4 cB = *reinterpret_cast<const float4*>(init_ws + b * NN2 + 2 * nbase + 4);
    __syncthreads();                // all waves done reading As/Bs
#pragma unroll
    for (int a = 0; a < 8; ++a) {
        int j = (a < 4) ? (jt * 4 + a) : (64 + jt * 4 + (a - 4));
        float rx = R1t[256 * 128 + j];
        float ry = R1t[257 * 128 + j];
        float bj = rb1[j];
        float4 hv;
        hv.x = fmaxf(acc[a][0] + rx * cA.x + ry * cA.y + bj, 0.f);
        hv.y = fmaxf(acc[a][1] + rx * cA.z + ry * cA.w + bj, 0.f);
        hv.z = fmaxf(acc[a][2] + rx * cB.x + ry * cB.y + bj, 0.f);
        hv.w = fmaxf(acc[a][3] + rx * cB.z + ry * cB.w + bj, 0.f);
        *reinterpret_cast<float4*>(&smem[j * 64 + nt * 4]) = hv;
    }
    __syncthreads();
    // phase 2: lane = point, each wave owns 16 j2 with wave-uniform
    // (readfirstlane) weight addresses -> s_loads.
    const int wave = tid >> 6, lane = tid & 63;
    const int jb = __builtin_amdgcn_readfirstlane(wave * 16);
    float a2[16];
#pragma unroll
    for (int jj = 0; jj < 16; ++jj) a2[jj] = rb2[jb + jj];
#pragma unroll 4
    for (int k = 0; k < 128; ++k) {
        float hv = smem[k * 64 + lane];
#pragma unroll
        for (int jj = 0; jj < 16; ++jj)
            a2[jj] = fmaf(R2[(jb + jj) * 128 + k], hv, a2[jj]);
    }
    float d0 = 0.f, d1 = 0.f;
#pragma unroll
    for (int jj = 0; jj < 16; ++jj) {
        float a = fmaxf(a2[jj], 0.f);
        d0 = fmaf(R3[jb + jj], a, d0);
        d1 = fmaf(R3[64 + jb + jj], a, d1);
    }
    float* part = &smem[8192];
    part[(wave * 2 + 0) * 64 + lane] = d0;
    part[(wave * 2 + 1) * 64 + lane] = d1;
    __syncthreads();
    if (tid < 64) {
        float s0 = 0.f, s1 = 0.f;
#pragma unroll
        for (int w = 0; w < 4; ++w) {
            s0 += part[(w * 2 + 0) * 64 + tid];
            s1 += part[(w * 2 + 1) * 64 + tid];
        }
        int n = n0 + tid;
        int nc = min(n, NPTS - 1);
        float2 ip = *reinterpret_cast<const float2*>(init_ws + b * NN2 + 2 * nc);
        float rx = fminf(fmaxf(ip.x + 0.1f * tanhf(s0 + rb3[0]), 0.f), 1.f);
        float ry = fminf(fmaxf(ip.y + 0.1f * tanhf(s1 + rb3[1]), 0.f), 1.f);
        if (n < NPTS) {
            *reinterpret_cast<float2*>(refined + ((size_t)b * NPTS + n) * 2)
                = make_float2(rx, ry);
        }
    }
}

// ---------------- kernel 5: v = sigmoid(relu(pf@V1^T+vb1)@V2^T+vb2), 320 rows
__global__ __launch_bounds__(256) void k_vhead(const float* __restrict__ refined,
                                               const float* __restrict__ V1t_g,
                                               const float* __restrict__ vb1,
                                               const float* __restrict__ V2,
                                               const float* __restrict__ vb2,
                                               float* __restrict__ vout) {
    __shared__ float V1t[100][128]; // [k][j]
    __shared__ float pf[4][100];
    const int tid = threadIdx.x, wave = tid >> 6, lane = tid & 63;
    for (int idx = tid; idx < 100 * 128; idx += 256)
        V1t[idx >> 7][idx & 127] = V1t_g[idx];  // coalesced
    __syncthreads();
    const int row = blockIdx.x * 4 + wave;      // [0,320)
    const float* src = refined + row * 100;
    if (lane < 50) {
        pf[wave][lane] = src[lane];
        pf[wave][lane + 50] = src[lane + 50];
    }
    __syncthreads();
    float a0 = vb1[lane], a1 = vb1[64 + lane];
#pragma unroll 10
    for (int k = 0; k < 100; ++k) {
        float p = pf[wave][k];
        a0 += V1t[k][lane] * p;
        a1 += V1t[k][64 + lane] * p;
    }
    float s = fmaxf(a0, 0.f) * V2[lane] + fmaxf(a1, 0.f) * V2[64 + lane];
#pragma unroll
    for (int off = 32; off > 0; off >>= 1) s += __shfl_xor(s, off, 64);
    if (lane == 0) vout[row] = 1.f / (1.f + expf(-(s + vb2[0])));
}

extern "C" void kernel_launch(void* const* d_in, const int* in_sizes, int n_in,
                              void* d_out, int out_size, void* d_ws, size_t ws_size,
                              hipStream_t stream) {
    const float* p4  = (const float*)d_in[0];
    const float* p2  = (const float*)d_in[1];
    // d_in[2] segmentation is unused by the reference
    const float* W1  = (const float*)d_in[3];
    const float* b1  = (const float*)d_in[4];
    const float* W2  = (const float*)d_in[5];
    const float* b2  = (const float*)d_in[6];
    const float* R1  = (const float*)d_in[7];
    const float* rb1 = (const float*)d_in[8];
    const float* R2  = (const float*)d_in[9];
    const float* rb2 = (const float*)d_in[10];
    const float* R3  = (const float*)d_in[11];
    const float* rb3 = (const float*)d_in[12];
    const float* V1  = (const float*)d_in[13];
    const float* vb1 = (const float*)d_in[14];
    const float* V2  = (const float*)d_in[15];
    const float* vb2 = (const float*)d_in[16];
    float* out = (float*)d_out;   // [refined 32000][v 320][init 32000]

    char* ws = (char*)d_ws;
    __hip_bfloat16* flat_bf = (__hip_bfloat16*)(ws + 0);       //   524,288 B
    float* h    = (float*)(ws + 524288);                       //    65,536 B
    float* ipts = (float*)(ws + 589824);                       //   128,000 B
    __hip_bfloat16* samp = (__hip_bfloat16*)(ws + 717824);     // 8,192,000 B
    float* R1t  = (float*)(ws + 8909824);                      //   132,096 B
    float* V1t_g= (float*)(ws + 9041920);                      //    51,200 B

    k_poolprep<<<1204, 256, 0, stream>>>(p4, R1, V1, flat_bf, R1t, V1t_g);
    k_fc1<<<256, 512, 0, stream>>>(flat_bf, W1, b1, h);
    k_fc2<<<500, 256, 0, stream>>>(h, W2, b2, ipts, out + 32320);
    k_sample<<<4096, 1024, 0, stream>>>(p2, ipts, samp);
    k_refine<<<256, 256, 0, stream>>>(samp, ipts, R1t, rb1, R2, rb2, R3, rb3, out);
    k_vhead<<<80, 256, 0, stream>>>(out, V1t_g, vb1, V2, vb2, out + 32000);
}